// Round 8
// baseline (926.137 us; speedup 1.0000x reference)
//
#include <hip/hip_runtime.h>
#include <math.h>

#define C 128

typedef unsigned short u16;
typedef __attribute__((ext_vector_type(8))) short short8;
typedef __attribute__((ext_vector_type(4))) float f32x4;

__device__ __forceinline__ float gelu_f(float v) {
    return 0.5f * v * (1.0f + erff(v * 0.70710678118654752f));
}

__device__ __forceinline__ u16 f2bf(float f) {
    unsigned u = __float_as_uint(f);
    unsigned r = (u + 0x7fffu + ((u >> 16) & 1u)) >> 16;
    return (u16)r;
}
__device__ __forceinline__ float b2f(u16 u) {
    return __uint_as_float(((unsigned)u) << 16);
}

__device__ __forceinline__ void g2lds16(const void* g, void* l) {
    __builtin_amdgcn_global_load_lds(
        (const __attribute__((address_space(1))) unsigned int*)g,
        (__attribute__((address_space(3))) unsigned int*)l, 16, 0, 0);
}

// ---------------------------------------------------------------------------
// Weight prep (unchanged from r5)
// ---------------------------------------------------------------------------
__global__ void prep_weights_kernel(const float* __restrict__ self_w,
                                    const float* __restrict__ self_b,
                                    const float* __restrict__ neigh_w,
                                    const float* __restrict__ neigh_b,
                                    const float* __restrict__ gate_w1,
                                    const float* __restrict__ gate_b1,
                                    float* __restrict__ Wc, float* __restrict__ bc,
                                    float* __restrict__ Wn1, float* __restrict__ bv,
                                    int L_) {
    const int y = blockIdx.y;
    const int i = blockIdx.x;
    const int j = threadIdx.x;
    if (y < L_) {
        const int l = y;
        const float* gw = gate_w1 + (size_t)l * 256 * C;  // top half
        if (i < C) {
            const float* swr = self_w + (size_t)l * C * C + (size_t)i * C;
            float s = 0.f;
            for (int k = 0; k < C; ++k) s += swr[k] * gw[k * C + j];
            Wc[(size_t)l * C * C + (size_t)i * C + j] = s;
        } else {
            const float* sbr = self_b + (size_t)l * C;
            float s = gate_b1[(size_t)l * C + j];
            for (int k = 0; k < C; ++k) s += sbr[k] * gw[k * C + j];
            bc[(size_t)l * C + j] = s;
        }
    } else {
        const int l = y - L_;
        const float* gw = gate_w1 + (size_t)l * 256 * C + (size_t)C * C;  // bottom half
        if (i < C) {
            const float* nwr = neigh_w + (size_t)l * C * C + (size_t)i * C;
            float s = 0.f;
            for (int k = 0; k < C; ++k) s += nwr[k] * gw[k * C + j];
            Wn1[(size_t)l * C * C + (size_t)i * C + j] = s;
        } else {
            const float* nbr = neigh_b + (size_t)l * C;
            float s = 0.f;
            for (int k = 0; k < C; ++k) s += nbr[k] * gw[k * C + j];
            bv[(size_t)l * C + j] = s;
        }
    }
}

// mats: 0=lw2, 1+l=gw2[l], 3+l=Wc[l], 5+l=Wn1[l]
__global__ void wsplit_kernel(const float* __restrict__ lw2, const float* __restrict__ gw2,
                              const float* __restrict__ Wc, const float* __restrict__ Wn1,
                              u16* __restrict__ wh, u16* __restrict__ wl) {
    const int col = blockIdx.x;
    const int mat = blockIdx.y;
    const int k = threadIdx.x;
    const float* src;
    if (mat == 0)      src = lw2;
    else if (mat <= 2) src = gw2 + (size_t)(mat - 1) * 16384;
    else if (mat <= 4) src = Wc + (size_t)(mat - 3) * 16384;
    else               src = Wn1 + (size_t)(mat - 5) * 16384;
    float v = src[k * C + col];
    u16 hi = f2bf(v);
    size_t di = (size_t)mat * 16384 + (size_t)col * C + k;
    wh[di] = hi;
    wl[di] = f2bf(v - b2f(hi));
}

__global__ void lift_hidden_kernel(const float* __restrict__ x,
                                   const float* __restrict__ w1,
                                   const float* __restrict__ b1,
                                   u16* __restrict__ oh, u16* __restrict__ ol, int N) {
    int idx = blockIdx.x * 256 + threadIdx.x;
    if (idx >= N * C) return;
    int n = idx >> 7, c = idx & 127;
    const float* xr = x + n * 9 + 3;
    float s = b1[c];
#pragma unroll
    for (int f = 0; f < 6; ++f) s += xr[f] * w1[f * C + c];
    s = gelu_f(s);
    u16 hi = f2bf(s);
    oh[idx] = hi;
    ol[idx] = f2bf(s - b2f(hi));
}

// ---------------------------------------------------------------------------
// Staging helper: stage one half-plane (128 rows x 64 u16) into LDS plane p.
// Linear LDS dest, pre-swizzled global source (chunk cl = (chunk&7)^(row&7)).
// ---------------------------------------------------------------------------
__device__ __forceinline__ void stage_plane(const u16* __restrict__ g, char* lds_base,
                                            int p, int t, int kh, int m0, int M,
                                            bool clampA) {
#pragma unroll
    for (int it = 0; it < 4; ++it) {
        int chunk = it * 256 + t;            // 0..1023
        int row = chunk >> 3;                // 0..127
        int cl = (chunk & 7) ^ (row & 7);    // pre-swizzled source chunk
        int grow = clampA ? ((m0 + row < M) ? m0 + row : M - 1) : row;
        const u16* src = g + (size_t)grow * C + kh * 64 + cl * 8;
        g2lds16(src, lds_base + (size_t)p * 16384 + chunk * 16);
    }
}

// ---------------------------------------------------------------------------
// Plain bf16x3 MFMA GEMM (used for lift only): out planes = A@W + bias
// ---------------------------------------------------------------------------
__global__ __launch_bounds__(256, 2)
void gemm_mfma_kernel(const u16* __restrict__ Ah_, const u16* __restrict__ Al_,
                      const u16* __restrict__ Wh_, const u16* __restrict__ Wl_,
                      const float* __restrict__ bias,
                      u16* __restrict__ Oh, u16* __restrict__ Ol, int M) {
    __shared__ __align__(16) char smem[65536];
    const int t = threadIdx.x;
    const int l = t & 63;
    const int w = t >> 6;
    const int wr = w >> 1, wc = w & 1;
    const int m0 = blockIdx.x * 128;
    const int kg = l >> 4;
    const int swz = l & 7;
    const int l15 = l & 15;

    f32x4 acc[4][4];
#pragma unroll
    for (int m = 0; m < 4; ++m)
#pragma unroll
        for (int n = 0; n < 4; ++n) acc[m][n] = (f32x4)(0.f);

    for (int kh = 0; kh < 2; ++kh) {
        stage_plane(Ah_, smem, 0, t, kh, m0, M, true);
        stage_plane(Al_, smem, 1, t, kh, m0, M, true);
        stage_plane(Wh_, smem, 2, t, kh, m0, M, false);
        stage_plane(Wl_, smem, 3, t, kh, m0, M, false);
        __syncthreads();
#pragma unroll
        for (int s = 0; s < 2; ++s) {
            const int ci = ((s * 4 + kg) ^ swz) * 16;
            short8 ah[4], al[4], bh[4], bl[4];
#pragma unroll
            for (int m = 0; m < 4; ++m) {
                int ro = (wr * 64 + m * 16 + l15) * 128;
                ah[m] = *(const short8*)(smem + ro + ci);
                al[m] = *(const short8*)(smem + 16384 + ro + ci);
            }
#pragma unroll
            for (int n = 0; n < 4; ++n) {
                int ro = (wc * 64 + n * 16 + l15) * 128;
                bh[n] = *(const short8*)(smem + 32768 + ro + ci);
                bl[n] = *(const short8*)(smem + 49152 + ro + ci);
            }
#pragma unroll
            for (int m = 0; m < 4; ++m)
#pragma unroll
                for (int n = 0; n < 4; ++n)
                    acc[m][n] = __builtin_amdgcn_mfma_f32_16x16x32_bf16(ah[m], bh[n], acc[m][n], 0, 0, 0);
#pragma unroll
            for (int m = 0; m < 4; ++m)
#pragma unroll
                for (int n = 0; n < 4; ++n)
                    acc[m][n] = __builtin_amdgcn_mfma_f32_16x16x32_bf16(al[m], bh[n], acc[m][n], 0, 0, 0);
#pragma unroll
            for (int m = 0; m < 4; ++m)
#pragma unroll
                for (int n = 0; n < 4; ++n)
                    acc[m][n] = __builtin_amdgcn_mfma_f32_16x16x32_bf16(ah[m], bl[n], acc[m][n], 0, 0, 0);
        }
        __syncthreads();
    }

    float bj[4];
#pragma unroll
    for (int n = 0; n < 4; ++n) bj[n] = bias[wc * 64 + n * 16 + l15];
#pragma unroll
    for (int m = 0; m < 4; ++m)
#pragma unroll
        for (int r = 0; r < 4; ++r) {
            int grow = m0 + wr * 64 + m * 16 + kg * 4 + r;
            if (grow < M) {
#pragma unroll
                for (int n = 0; n < 4; ++n) {
                    int col = wc * 64 + n * 16 + l15;
                    float o = acc[m][n][r] + bj[n];
                    size_t idx = (size_t)grow * C + col;
                    u16 hi = f2bf(o);
                    Oh[idx] = hi;
                    Ol[idx] = f2bf(o - b2f(hi));
                }
            }
        }
}

// ---------------------------------------------------------------------------
// Fused layer kernel: gate1 (2-source GEMM) + gelu + gate2 GEMM + resid,
// u1 routed through LDS (never to HBM). Last layer: fused LayerNorm -> fp32.
//   u1  = gelu(h@Wc + aggrH@Wn1 + bc + sumev*bv)
//   h'  = h + u1@gw2 + gb2      (or LN(h') -> outF on last layer)
// ---------------------------------------------------------------------------
__global__ __launch_bounds__(256, 2)
void fused_layer_kernel(const u16* __restrict__ Hh, const u16* __restrict__ Hl,
                        const u16* __restrict__ Chh, const u16* __restrict__ Cll,
                        const u16* __restrict__ wch, const u16* __restrict__ wcl,
                        const u16* __restrict__ n1h, const u16* __restrict__ n1l,
                        const u16* __restrict__ g2h, const u16* __restrict__ g2l,
                        const float* __restrict__ bc, const float* __restrict__ bv,
                        const float* __restrict__ sumev,
                        const float* __restrict__ gb2,
                        u16* __restrict__ OHh, u16* __restrict__ OHl,
                        const float* __restrict__ lng, const float* __restrict__ lnb,
                        float* __restrict__ outF,
                        int M) {
    __shared__ __align__(16) char smem[128 * 132 * 4];  // 67584 B (>= 64KB planes)
    const int t = threadIdx.x;
    const int l = t & 63;
    const int w = t >> 6;
    const int wr = w >> 1, wc = w & 1;
    const int m0 = blockIdx.x * 128;
    const int kg = l >> 4;
    const int swz = l & 7;
    const int l15 = l & 15;

    f32x4 acc[4][4];
#pragma unroll
    for (int m = 0; m < 4; ++m)
#pragma unroll
        for (int n = 0; n < 4; ++n) acc[m][n] = (f32x4)(0.f);

    // ---- phase A: gate1, two sources x two K-halves ----
    for (int sidx = 0; sidx < 2; ++sidx) {
        const u16* Ah_ = sidx ? Chh : Hh;
        const u16* Al_ = sidx ? Cll : Hl;
        const u16* Wh_ = sidx ? n1h : wch;
        const u16* Wl_ = sidx ? n1l : wcl;
        for (int kh = 0; kh < 2; ++kh) {
            stage_plane(Ah_, smem, 0, t, kh, m0, M, true);
            stage_plane(Al_, smem, 1, t, kh, m0, M, true);
            stage_plane(Wh_, smem, 2, t, kh, m0, M, false);
            stage_plane(Wl_, smem, 3, t, kh, m0, M, false);
            __syncthreads();
#pragma unroll
            for (int s = 0; s < 2; ++s) {
                const int ci = ((s * 4 + kg) ^ swz) * 16;
                short8 ah[4], al[4], bh[4], bl[4];
#pragma unroll
                for (int m = 0; m < 4; ++m) {
                    int ro = (wr * 64 + m * 16 + l15) * 128;
                    ah[m] = *(const short8*)(smem + ro + ci);
                    al[m] = *(const short8*)(smem + 16384 + ro + ci);
                }
#pragma unroll
                for (int n = 0; n < 4; ++n) {
                    int ro = (wc * 64 + n * 16 + l15) * 128;
                    bh[n] = *(const short8*)(smem + 32768 + ro + ci);
                    bl[n] = *(const short8*)(smem + 49152 + ro + ci);
                }
#pragma unroll
                for (int m = 0; m < 4; ++m)
#pragma unroll
                    for (int n = 0; n < 4; ++n)
                        acc[m][n] = __builtin_amdgcn_mfma_f32_16x16x32_bf16(ah[m], bh[n], acc[m][n], 0, 0, 0);
#pragma unroll
                for (int m = 0; m < 4; ++m)
#pragma unroll
                    for (int n = 0; n < 4; ++n)
                        acc[m][n] = __builtin_amdgcn_mfma_f32_16x16x32_bf16(al[m], bh[n], acc[m][n], 0, 0, 0);
#pragma unroll
                for (int m = 0; m < 4; ++m)
#pragma unroll
                    for (int n = 0; n < 4; ++n)
                        acc[m][n] = __builtin_amdgcn_mfma_f32_16x16x32_bf16(ah[m], bl[n], acc[m][n], 0, 0, 0);
            }
            __syncthreads();
        }
    }

    // ---- epilogue 1: u1 = gelu(acc + bc + sumev*bv), kept in acc regs ----
    {
        float bj[4], b2j[4];
#pragma unroll
        for (int n = 0; n < 4; ++n) {
            bj[n] = bc[wc * 64 + n * 16 + l15];
            b2j[n] = bv[wc * 64 + n * 16 + l15];
        }
#pragma unroll
        for (int m = 0; m < 4; ++m)
#pragma unroll
            for (int r = 0; r < 4; ++r) {
                int grow = m0 + wr * 64 + m * 16 + kg * 4 + r;
                float rs_ = (grow < M) ? sumev[grow] : 0.f;
#pragma unroll
                for (int n = 0; n < 4; ++n)
                    acc[m][n][r] = gelu_f(acc[m][n][r] + bj[n] + rs_ * b2j[n]);
            }
    }

    // ---- phase B: gate2, A = u1 via LDS (planes 0,1), W = gw2 (planes 2,3) ----
    f32x4 acc2[4][4];
#pragma unroll
    for (int m = 0; m < 4; ++m)
#pragma unroll
        for (int n = 0; n < 4; ++n) acc2[m][n] = (f32x4)(0.f);

    for (int kh = 0; kh < 2; ++kh) {
        // write this K-half of u1 into planes 0,1 (only waves owning those cols)
        if (wc == kh) {
#pragma unroll
            for (int m = 0; m < 4; ++m)
#pragma unroll
                for (int r = 0; r < 4; ++r) {
                    int rowl = wr * 64 + m * 16 + kg * 4 + r;
                    int rb = rowl * 128;
#pragma unroll
                    for (int n = 0; n < 4; ++n) {
                        int colk = n * 16 + l15;               // k within slice, 0..63
                        int pb = ((colk >> 3) ^ (rowl & 7)) * 16 + (colk & 7) * 2;
                        float v = acc[m][n][r];
                        u16 hi = f2bf(v);
                        *(u16*)(smem + rb + pb) = hi;
                        *(u16*)(smem + 16384 + rb + pb) = f2bf(v - b2f(hi));
                    }
                }
        }
        stage_plane(g2h, smem, 2, t, kh, m0, M, false);
        stage_plane(g2l, smem, 3, t, kh, m0, M, false);
        __syncthreads();
#pragma unroll
        for (int s = 0; s < 2; ++s) {
            const int ci = ((s * 4 + kg) ^ swz) * 16;
            short8 ah[4], al[4], bh[4], bl[4];
#pragma unroll
            for (int m = 0; m < 4; ++m) {
                int ro = (wr * 64 + m * 16 + l15) * 128;
                ah[m] = *(const short8*)(smem + ro + ci);
                al[m] = *(const short8*)(smem + 16384 + ro + ci);
            }
#pragma unroll
            for (int n = 0; n < 4; ++n) {
                int ro = (wc * 64 + n * 16 + l15) * 128;
                bh[n] = *(const short8*)(smem + 32768 + ro + ci);
                bl[n] = *(const short8*)(smem + 49152 + ro + ci);
            }
#pragma unroll
            for (int m = 0; m < 4; ++m)
#pragma unroll
                for (int n = 0; n < 4; ++n)
                    acc2[m][n] = __builtin_amdgcn_mfma_f32_16x16x32_bf16(ah[m], bh[n], acc2[m][n], 0, 0, 0);
#pragma unroll
            for (int m = 0; m < 4; ++m)
#pragma unroll
                for (int n = 0; n < 4; ++n)
                    acc2[m][n] = __builtin_amdgcn_mfma_f32_16x16x32_bf16(al[m], bh[n], acc2[m][n], 0, 0, 0);
#pragma unroll
            for (int m = 0; m < 4; ++m)
#pragma unroll
                for (int n = 0; n < 4; ++n)
                    acc2[m][n] = __builtin_amdgcn_mfma_f32_16x16x32_bf16(ah[m], bl[n], acc2[m][n], 0, 0, 0);
        }
        __syncthreads();
    }

    // ---- epilogue 2: h' = acc2 + gb2 + h ----
    float* lnt = (float*)smem;
    float bj2[4];
#pragma unroll
    for (int n = 0; n < 4; ++n) bj2[n] = gb2[wc * 64 + n * 16 + l15];
#pragma unroll
    for (int m = 0; m < 4; ++m)
#pragma unroll
        for (int r = 0; r < 4; ++r) {
            int rowl = wr * 64 + m * 16 + kg * 4 + r;
            int grow = m0 + rowl;
            bool ok = grow < M;
#pragma unroll
            for (int n = 0; n < 4; ++n) {
                int col = wc * 64 + n * 16 + l15;
                size_t idx = (size_t)grow * C + col;
                float o = acc2[m][n][r] + bj2[n];
                if (ok) o += b2f(Hh[idx]) + b2f(Hl[idx]);
                if (outF) {
                    lnt[rowl * 132 + col] = o;
                } else if (ok) {
                    u16 hi = f2bf(o);
                    OHh[idx] = hi;
                    OHl[idx] = f2bf(o - b2f(hi));
                }
            }
        }

    if (outF) {
        __syncthreads();
        float2 gg = *(const float2*)&lng[l << 1];
        float2 bb = *(const float2*)&lnb[l << 1];
        for (int r = 0; r < 32; ++r) {
            int rowl = w * 32 + r;
            int grow = m0 + rowl;
            if (grow >= M) break;
            float2 v = *(const float2*)&lnt[rowl * 132 + (l << 1)];
            float s = v.x + v.y;
#pragma unroll
            for (int mk = 1; mk < 64; mk <<= 1) s += __shfl_xor(s, mk, 64);
            float mu = s * (1.f / 128.f);
            float dx = v.x - mu, dy = v.y - mu;
            float q = dx * dx + dy * dy;
#pragma unroll
            for (int mk = 1; mk < 64; mk <<= 1) q += __shfl_xor(q, mk, 64);
            float rsq = 1.f / sqrtf(q * (1.f / 128.f) + 1e-5f);
            float2 o;
            o.x = dx * rsq * gg.x + bb.x;
            o.y = dy * rsq * gg.y + bb.y;
            *(float2*)&outF[(size_t)grow * C + (l << 1)] = o;
        }
    }
}

// ---------------------------------------------------------------------------
// CSR build (unchanged)
// ---------------------------------------------------------------------------
__global__ void zero_i32_kernel(int* __restrict__ p, int n) {
    int i = blockIdx.x * 256 + threadIdx.x;
    if (i < n) p[i] = 0;
}

__global__ void deg_count_kernel(const int* __restrict__ row, int* __restrict__ deg, int E) {
    int e = blockIdx.x * 256 + threadIdx.x;
    if (e < E) atomicAdd(&deg[row[e]], 1);
}

__global__ void scan_chunk_kernel(const int* __restrict__ deg, int* __restrict__ offs,
                                  int* __restrict__ part, int N) {
    __shared__ int ts[256];
    const int t = threadIdx.x;
    const int base = blockIdx.x * 1024 + t * 4;
    int v0 = (base + 0 < N) ? deg[base + 0] : 0;
    int v1 = (base + 1 < N) ? deg[base + 1] : 0;
    int v2 = (base + 2 < N) ? deg[base + 2] : 0;
    int v3 = (base + 3 < N) ? deg[base + 3] : 0;
    int l0 = v0, l1 = l0 + v1, l2 = l1 + v2, l3 = l2 + v3;
    ts[t] = l3;
    __syncthreads();
    for (int d = 1; d < 256; d <<= 1) {
        int add = (t >= d) ? ts[t - d] : 0;
        __syncthreads();
        ts[t] += add;
        __syncthreads();
    }
    int tex = ts[t] - l3;
    if (base + 0 < N) offs[base + 1] = tex + l0;
    if (base + 1 < N) offs[base + 2] = tex + l1;
    if (base + 2 < N) offs[base + 3] = tex + l2;
    if (base + 3 < N) offs[base + 4] = tex + l3;
    if (t == 255) part[blockIdx.x] = ts[255];
}

__global__ void scan_partials_kernel(int* __restrict__ part, int n) {
    __shared__ int s[128];
    const int t = threadIdx.x;
    int v = (t < n) ? part[t] : 0;
    s[t] = v;
    __syncthreads();
    for (int d = 1; d < 128; d <<= 1) {
        int add = (t >= d) ? s[t - d] : 0;
        __syncthreads();
        s[t] += add;
        __syncthreads();
    }
    if (t < n) part[t] = s[t] - v;
}

__global__ void scan_add_kernel(int* __restrict__ offs, const int* __restrict__ part,
                                int* __restrict__ cursor, int N) {
    const int t = threadIdx.x;
    const int base = blockIdx.x * 1024 + t * 4;
    const int add = part[blockIdx.x];
#pragma unroll
    for (int j = 0; j < 4; ++j) {
        int i = base + j;
        if (i < N) {
            int v = offs[i + 1] + add;
            offs[i + 1] = v;
            if (i + 1 < N) cursor[i + 1] = v;
        }
    }
    if (blockIdx.x == 0 && t == 0) {
        offs[0] = 0;
        cursor[0] = 0;
    }
}

__global__ void fill_kernel(const int* __restrict__ row, const int* __restrict__ col,
                            const float* __restrict__ ev, int* __restrict__ cursor,
                            int2* __restrict__ epack, int E) {
    int e = blockIdx.x * 256 + threadIdx.x;
    if (e >= E) return;
    int r = row[e];
    int pos = atomicAdd(&cursor[r], 1);
    int2 p;
    p.x = col[e];
    p.y = __float_as_int(ev[e]);
    epack[pos] = p;
}

// ---------------------------------------------------------------------------
// Aggregation (gather), unrolled x4 for MLP: aggrH[d]=sum ev*h[col], sumev[d]
// ---------------------------------------------------------------------------
__global__ __launch_bounds__(256)
void aggregate_kernel(const u16* __restrict__ nh, const u16* __restrict__ nl,
                      const int* __restrict__ offs, const int2* __restrict__ epack,
                      u16* __restrict__ oh, u16* __restrict__ ol,
                      float* __restrict__ sumev, int N) {
    const int lane = threadIdx.x & 63;
    const int node = (blockIdx.x << 2) + (threadIdx.x >> 6);
    if (node >= N) return;
    const int s = offs[node], e = offs[node + 1];
    const int ch = lane << 1;
    float a0x = 0.f, a0y = 0.f, a1x = 0.f, a1y = 0.f;
    float a2x = 0.f, a2y = 0.f, a3x = 0.f, a3y = 0.f;
    float ssum = 0.f;
    int i = s;
    for (; i + 4 <= e; i += 4) {
        int2 p0 = epack[i];
        int2 p1 = epack[i + 1];
        int2 p2 = epack[i + 2];
        int2 p3 = epack[i + 3];
        float v0 = __int_as_float(p0.y), v1 = __int_as_float(p1.y);
        float v2 = __int_as_float(p2.y), v3 = __int_as_float(p3.y);
        ushort2 h0 = *(const ushort2*)&nh[(size_t)p0.x * C + ch];
        ushort2 h1 = *(const ushort2*)&nh[(size_t)p1.x * C + ch];
        ushort2 h2 = *(const ushort2*)&nh[(size_t)p2.x * C + ch];
        ushort2 h3 = *(const ushort2*)&nh[(size_t)p3.x * C + ch];
        ushort2 q0 = *(const ushort2*)&nl[(size_t)p0.x * C + ch];
        ushort2 q1 = *(const ushort2*)&nl[(size_t)p1.x * C + ch];
        ushort2 q2 = *(const ushort2*)&nl[(size_t)p2.x * C + ch];
        ushort2 q3 = *(const ushort2*)&nl[(size_t)p3.x * C + ch];
        a0x += v0 * (b2f(h0.x) + b2f(q0.x)); a0y += v0 * (b2f(h0.y) + b2f(q0.y));
        a1x += v1 * (b2f(h1.x) + b2f(q1.x)); a1y += v1 * (b2f(h1.y) + b2f(q1.y));
        a2x += v2 * (b2f(h2.x) + b2f(q2.x)); a2y += v2 * (b2f(h2.y) + b2f(q2.y));
        a3x += v3 * (b2f(h3.x) + b2f(q3.x)); a3y += v3 * (b2f(h3.y) + b2f(q3.y));
        ssum += (v0 + v1) + (v2 + v3);
    }
    for (; i < e; ++i) {
        int2 p = epack[i];
        float v = __int_as_float(p.y);
        ushort2 h0 = *(const ushort2*)&nh[(size_t)p.x * C + ch];
        ushort2 q0 = *(const ushort2*)&nl[(size_t)p.x * C + ch];
        a0x += v * (b2f(h0.x) + b2f(q0.x));
        a0y += v * (b2f(h0.y) + b2f(q0.y));
        ssum += v;
    }
    float sx = (a0x + a1x) + (a2x + a3x);
    float sy = (a0y + a1y) + (a2y + a3y);
    ushort2 ho, lo;
    ho.x = f2bf(sx); ho.y = f2bf(sy);
    lo.x = f2bf(sx - b2f(ho.x)); lo.y = f2bf(sy - b2f(ho.y));
    size_t idx = (size_t)node * C + ch;
    *(ushort2*)&oh[idx] = ho;
    *(ushort2*)&ol[idx] = lo;
    if (lane == 0) sumev[node] = ssum;
}

// ---------------------------------------------------------------------------
extern "C" void kernel_launch(void* const* d_in, const int* in_sizes, int n_in,
                              void* d_out, int out_size, void* d_ws, size_t ws_size,
                              hipStream_t stream) {
    const float* x    = (const float*)d_in[0];
    const int*   ei   = (const int*)d_in[1];
    const float* ev   = (const float*)d_in[2];
    const float* lw1  = (const float*)d_in[3];
    const float* lb1  = (const float*)d_in[4];
    const float* lw2  = (const float*)d_in[5];
    const float* lb2  = (const float*)d_in[6];
    const float* sw   = (const float*)d_in[7];
    const float* sb   = (const float*)d_in[8];
    const float* nw   = (const float*)d_in[9];
    const float* nbi  = (const float*)d_in[10];
    const float* gw1  = (const float*)d_in[11];
    const float* gb1  = (const float*)d_in[12];
    const float* gw2  = (const float*)d_in[13];
    const float* gb2  = (const float*)d_in[14];
    const float* ng   = (const float*)d_in[15];
    const float* nbt  = (const float*)d_in[16];

    const int N = in_sizes[0] / 9;
    const int E = in_sizes[2];
    const int L = in_sizes[7] / (C * C);
    const int* row = ei;
    const int* col = ei + E;

    float* out = (float*)d_out;

    // workspace carve
    char* p = (char*)d_ws;
    u16* Hh = (u16*)p; p += (size_t)N * C * 2;   // h planes
    u16* Hl = (u16*)p; p += (size_t)N * C * 2;
    u16* Bh = (u16*)p; p += (size_t)N * C * 2;   // lift hid planes
    u16* Bl = (u16*)p; p += (size_t)N * C * 2;
    u16* Ch = (u16*)p; p += (size_t)N * C * 2;   // aggrH planes
    u16* Cl = (u16*)p; p += (size_t)N * C * 2;
    int2* epack = (int2*)p; p += (size_t)E * sizeof(int2);
    float* Wc  = (float*)p; p += (size_t)L * C * C * sizeof(float);
    float* Wn1 = (float*)p; p += (size_t)L * C * C * sizeof(float);
    float* bc  = (float*)p; p += (size_t)L * C * sizeof(float);
    float* bv  = (float*)p; p += (size_t)L * C * sizeof(float);
    float* sumev = (float*)p; p += (size_t)N * sizeof(float);
    u16* wh = (u16*)p; p += (size_t)7 * C * C * 2;
    u16* wl = (u16*)p; p += (size_t)7 * C * C * 2;
    int* deg    = (int*)p; p += (size_t)N * sizeof(int);
    int* offs   = (int*)p; p += (size_t)(N + 1) * sizeof(int);
    int* cursor = (int*)p; p += (size_t)N * sizeof(int);
    int* part   = (int*)p; p += 1024 * sizeof(int);

    const int NB_SCAN = (N + 1023) / 1024;
    const int GB_NODE = (N + 3) / 4;
    const int GB_EDGE = (E + 255) / 256;
    const int GB_GEMM = (N + 127) / 128;

    prep_weights_kernel<<<dim3(C + 1, 2 * L), C, 0, stream>>>(
        sw, sb, nw, nbi, gw1, gb1, Wc, bc, Wn1, bv, L);
    wsplit_kernel<<<dim3(C, 7), C, 0, stream>>>(lw2, gw2, Wc, Wn1, wh, wl);

    // lift
    lift_hidden_kernel<<<(N * C + 255) / 256, 256, 0, stream>>>(x, lw1, lb1, Bh, Bl, N);
    gemm_mfma_kernel<<<GB_GEMM, 256, 0, stream>>>(Bh, Bl, wh, wl, lb2, Hh, Hl, N);

    // CSR build
    zero_i32_kernel<<<(N + 255) / 256, 256, 0, stream>>>(deg, N);
    deg_count_kernel<<<GB_EDGE, 256, 0, stream>>>(row, deg, E);
    scan_chunk_kernel<<<NB_SCAN, 256, 0, stream>>>(deg, offs, part, N);
    scan_partials_kernel<<<1, 128, 0, stream>>>(part, NB_SCAN);
    scan_add_kernel<<<NB_SCAN, 256, 0, stream>>>(offs, part, cursor, N);
    fill_kernel<<<GB_EDGE, 256, 0, stream>>>(row, col, ev, cursor, epack, E);

    for (int l = 0; l < L; ++l) {
        const u16* g2h = wh + (size_t)(1 + l) * 16384;
        const u16* g2l = wl + (size_t)(1 + l) * 16384;
        const u16* wch = wh + (size_t)(3 + l) * 16384;
        const u16* wcl = wl + (size_t)(3 + l) * 16384;
        const u16* n1h = wh + (size_t)(5 + l) * 16384;
        const u16* n1l = wl + (size_t)(5 + l) * 16384;
        const bool last = (l == L - 1);

        aggregate_kernel<<<GB_NODE, 256, 0, stream>>>(Hh, Hl, offs, epack, Ch, Cl, sumev, N);
        fused_layer_kernel<<<GB_GEMM, 256, 0, stream>>>(
            Hh, Hl, Ch, Cl, wch, wcl, n1h, n1l, g2h, g2l,
            bc + (size_t)l * C, bv + (size_t)l * C, sumev,
            gb2 + (size_t)l * C,
            Hh, Hl,
            last ? ng : nullptr, last ? nbt : nullptr, last ? out : nullptr,
            N);
    }
}